// Round 10
// baseline (574.483 us; speedup 1.0000x reference)
//
#include <hip/hip_runtime.h>
#include <hip/hip_bf16.h>

// HieraMaskUnitAttention on MI355X (gfx950).
// B=8 T=8192 D=768 H=12 HD=64 Q_STRIDE=4 WINDOW=64 -> nw=32, seq=256, q_len=64
//
// Pipeline (R10):
//   1) cvt_w2: qkv_w + proj_w fp32->bf16 (ONE launch). cvt_emb DELETED.
//   2) gemmf32a<bf16 out>: qkv = emb(fp32) @ qkv_w^T + qkv_b
//      Per-tile grid 4608 (BM=128 BN=256), XCD-bijective N-fast (A read ~once,
//      R8-proven). A staged fp32 via global_load_lds DMA (R8's reg-stage latency
//      trap avoided); LDS->reg fp32 then v_cvt_pk_bf16_f32 AFTER the barrier.
//      2 phases/K-step (half the barriers of the 256^2 structure), 16 MFMA/phase.
//   3) attn_kernel (R7): Q max-pool, QK^T softmax (attn fp32 -> d_out), PV -> X ws
//   4) gemm256t<f32 out>: out = X @ proj_w^T + proj_b (256^2 per-tile, 192 blocks)
//
// CLOSED BRANCHES (measured): persistent+fp32A (R6: L3 blowout); reg-staged A
// (R8: latency exposed); GEMM micro-schedule variants (R3-R5: all 37% MfmaUtil).

typedef float  f32x4  __attribute__((ext_vector_type(4)));
typedef __bf16 bf16x8 __attribute__((ext_vector_type(8)));

__device__ __forceinline__ unsigned short f2bf(float f) {
  unsigned int u = __float_as_uint(f);
  u += 0x7fffu + ((u >> 16) & 1u);      // RNE
  return (unsigned short)(u >> 16);
}
__device__ __forceinline__ float bf2f(unsigned short b) {
  return __uint_as_float(((unsigned int)b) << 16);
}

#define GLOAD_LDS16(gptr, lptr) __builtin_amdgcn_global_load_lds( \
    (const __attribute__((address_space(1))) void*)(gptr),        \
    (__attribute__((address_space(3))) void*)(lptr), 16, 0, 0)

// ---------------------------------------------------------------- cvt weights
__global__ void cvt_w2(const float* __restrict__ s1, unsigned short* __restrict__ d1,
                       int n1_4,
                       const float* __restrict__ s2, unsigned short* __restrict__ d2,
                       int n2_4) {
  int i = blockIdx.x * blockDim.x + threadIdx.x;
  const int stride = gridDim.x * blockDim.x;
  const int tot = n1_4 + n2_4;
  for (; i < tot; i += stride) {
    const float4 v = (i < n1_4) ? ((const float4*)s1)[i]
                                : ((const float4*)s2)[i - n1_4];
    ushort4 o;
    o.x = f2bf(v.x); o.y = f2bf(v.y); o.z = f2bf(v.z); o.w = f2bf(v.w);
    if (i < n1_4) ((ushort4*)d1)[i] = o;
    else          ((ushort4*)d2)[i - n1_4] = o;
  }
}

// ---------------------------------------------------------------- fused fp32-A GEMM
// C = A(fp32) @ B(bf16)^T + bias. A: [M x K] f32 K-fast, B: [N x K] bf16 K-fast.
// BM=128 BN=256 BK=64(=2 kh of 32). 8 waves (2M x 4N), per-wave C 64x64.
// Grid (M/128)*(N/256), XCD-bijective, N-fast (9 consecutive wg share A-panel).
// LDS 128KB: A(par,kh) fp32 [128r x 32k] @ par*32768+kh*16384 (16KB each);
//            B(par,kh) bf16 [256r x 32k] @ 65536+par*32768+kh*16384.
// Per K-tile t: ph1 {read kh0 | stage A+B kh1(t+1)->parn | vmcnt(8) | BAR |
//               cvt+16 MFMA | BAR}; ph2 {read kh1 | stage A+B kh0(t+2)->par |
//               vmcnt(8) | BAR | cvt+16 MFMA | BAR}.
// Ledger (4 loads/phase): vmcnt(8) in phase p drains exactly the stage of phase
// p-2; its readers run in phase p+1 (>=1 barrier after the drain, all waves).
// WAR: readers lgkm-drain before their MFMA < BAR < restage issue.
// Swizzle A: slot(16B of 8/row) ^= row&7 (2 lanes/bank on reads: free).
// Swizzle B: slot(16B of 4/row) ^= row&3 (4-way on 4 reads/phase: accepted).
template <int OUT_BF16>
__global__ __launch_bounds__(512, 2) void gemmf32a(
    const float* __restrict__ A, const unsigned short* __restrict__ B,
    const float* __restrict__ bias, void* __restrict__ Cout,
    int M, int N, int K) {
  extern __shared__ char lds[];

  const int tid  = threadIdx.x;
  const int lane = tid & 63;
  const int wid  = tid >> 6;
  const int g16  = (lane >> 4) & 3;
  const int l15  = lane & 15;
  const int wm   = wid >> 2;      // 0..1
  const int wn   = wid & 3;       // 0..3

  const int nbn = N >> 8;
  const int wg  = (blockIdx.x & 7) * ((int)gridDim.x >> 3) + (blockIdx.x >> 3);
  const size_t bm = (size_t)(wg / nbn) << 7;
  const size_t bn = (size_t)(wg % nbn) << 8;

  const int NT = K >> 6;          // 12

  // ---- staging thread-constants (pre-swizzled global source, linear dest) ----
  const int rowA = wid * 16 + (lane >> 3);          // j=1 adds +8 (same &7)
  const int slA  = lane & 7;
  const float* pA0 = A + (bm + rowA) * (size_t)K + ((slA ^ (rowA & 7)) << 2);
  const float* pA1 = pA0 + (size_t)8 * K;
  const int rowB = wid * 32 + (lane >> 2);          // j=1 adds +16 (same &3)
  const int slB  = lane & 3;
  const unsigned short* pB0 = B + (bn + rowB) * (size_t)K + ((slB ^ (rowB & 3)) << 3);
  const unsigned short* pB1 = pB0 + (size_t)16 * K;
  const int dW = wid * 2048;                        // wave-uniform dest base

#define STAGE_A(koff, regbase)                                          \
  do {                                                                  \
    GLOAD_LDS16(pA0 + (koff), lds + (regbase) + dW);                    \
    GLOAD_LDS16(pA1 + (koff), lds + (regbase) + dW + 1024);             \
  } while (0)
#define STAGE_B(boff, regbase)                                          \
  do {                                                                  \
    GLOAD_LDS16(pB0 + (boff), lds + (regbase) + dW);                    \
    GLOAD_LDS16(pB1 + (boff), lds + (regbase) + dW + 1024);             \
  } while (0)

  // ---- fragment-read constants ----
  const int sA0    = ((2 * g16) ^ (l15 & 7)) << 4;
  const int sA1    = ((2 * g16 + 1) ^ (l15 & 7)) << 4;
  const int baseAr = (wm * 64 + l15) * 128;         // + m*2048 + region
  const int sBr    = (g16 ^ (l15 & 3)) << 4;
  const int baseBr = (wn * 64 + l15) * 64;          // + n*1024 + region

  f32x4 acc[4][4];
  const f32x4 zero4 = {0.f, 0.f, 0.f, 0.f};
#pragma unroll
  for (int i = 0; i < 4; ++i)
#pragma unroll
    for (int j = 0; j < 4; ++j) acc[i][j] = zero4;

  f32x4 alo[4], ahi[4];
  bf16x8 af[4], bfv[4];
  union QU { int4 i; bf16x8 v; };

#define READ_A(par, kh)                                                   \
  { const char* ra = lds + (par) * 32768 + (kh) * 16384 + baseAr;         \
    _Pragma("unroll") for (int m = 0; m < 4; ++m) {                       \
      alo[m] = *(const f32x4*)(ra + m * 2048 + sA0);                      \
      ahi[m] = *(const f32x4*)(ra + m * 2048 + sA1);                      \
    } }
#define CVT_A()                                                           \
  { _Pragma("unroll") for (int m = 0; m < 4; ++m) {                       \
      QU q;                                                               \
      asm("v_cvt_pk_bf16_f32 %0, %1, %2" : "=v"(q.i.x) : "v"(alo[m][0]), "v"(alo[m][1])); \
      asm("v_cvt_pk_bf16_f32 %0, %1, %2" : "=v"(q.i.y) : "v"(alo[m][2]), "v"(alo[m][3])); \
      asm("v_cvt_pk_bf16_f32 %0, %1, %2" : "=v"(q.i.z) : "v"(ahi[m][0]), "v"(ahi[m][1])); \
      asm("v_cvt_pk_bf16_f32 %0, %1, %2" : "=v"(q.i.w) : "v"(ahi[m][2]), "v"(ahi[m][3])); \
      af[m] = q.v;                                                        \
    } }
#define READ_B(par, kh)                                                   \
  { const char* rb = lds + 65536 + (par) * 32768 + (kh) * 16384 + baseBr + sBr; \
    bfv[0] = *(const bf16x8*)(rb);                                        \
    bfv[1] = *(const bf16x8*)(rb + 1024);                                 \
    bfv[2] = *(const bf16x8*)(rb + 2048);                                 \
    bfv[3] = *(const bf16x8*)(rb + 3072); }
#define MFMA16()                                                          \
  _Pragma("unroll") for (int m = 0; m < 4; ++m)                           \
  _Pragma("unroll") for (int n = 0; n < 4; ++n)                           \
    acc[m][n] = __builtin_amdgcn_mfma_f32_16x16x32_bf16(                  \
        af[m], bfv[n], acc[m][n], 0, 0, 0);
#define BAR() __builtin_amdgcn_s_barrier()
#define VMCNT8() asm volatile("s_waitcnt vmcnt(8)" ::: "memory")

  // ---- prologue: kh0(0), kh1(0), kh0(1); drain kh0(0) ----
  STAGE_A(0, 0);              STAGE_B(0, 65536);
  STAGE_A(32, 16384);         STAGE_B(32, 65536 + 16384);
  STAGE_A(64, 32768);         STAGE_B(64, 65536 + 32768);
  VMCNT8();
  BAR();

  for (int t = 0; t < NT; ++t) {
    const int par  = t & 1;
    const int parn = par ^ 1;
    const int kc1  = (t + 1 < NT ? t + 1 : NT - 1) * 64;
    const int kc2  = (t + 2 < NT ? t + 2 : NT - 1) * 64;

    // ph1: kh0 | stage kh1(t+1) -> parn
    READ_A(par, 0); READ_B(par, 0);
    STAGE_A(kc1 + 32, parn * 32768 + 16384);
    STAGE_B(kc1 + 32, 65536 + parn * 32768 + 16384);
    VMCNT8();
    BAR();
    CVT_A();
    __builtin_amdgcn_s_setprio(1); MFMA16(); __builtin_amdgcn_s_setprio(0);
    BAR();

    // ph2: kh1 | stage kh0(t+2) -> par
    READ_A(par, 1); READ_B(par, 1);
    STAGE_A(kc2, par * 32768);
    STAGE_B(kc2, 65536 + par * 32768);
    VMCNT8();
    BAR();
    CVT_A();
    __builtin_amdgcn_s_setprio(1); MFMA16(); __builtin_amdgcn_s_setprio(0);
    BAR();
  }

  // ---- epilogue: + bias, store ----
#pragma unroll
  for (int m = 0; m < 4; ++m) {
    const size_t row0 = bm + wm * 64 + m * 16 + g16 * 4;
#pragma unroll
    for (int n = 0; n < 4; ++n) {
      const size_t col = bn + wn * 64 + n * 16 + l15;
      const float bv = bias[col];
#pragma unroll
      for (int r = 0; r < 4; ++r) {
        const float v = acc[m][n][r] + bv;
        const size_t idx = (row0 + r) * N + col;
        if (OUT_BF16) ((unsigned short*)Cout)[idx] = f2bf(v);
        else          ((float*)Cout)[idx] = v;
      }
    }
  }
#undef STAGE_A
#undef STAGE_B
#undef READ_A
#undef CVT_A
#undef READ_B
#undef MFMA16
#undef BAR
#undef VMCNT8
}

// ---------------------------------------------------------------- per-tile 256x256 GEMM
// C = A @ B^T + bias, both bf16 K-fast. (R9 proj kernel, unchanged.)
template <int OUT_BF16>
__global__ __launch_bounds__(512, 2) void gemm256t(
    const unsigned short* __restrict__ A, const unsigned short* __restrict__ B,
    const float* __restrict__ bias, void* __restrict__ Cout,
    int M, int N, int K) {
  extern __shared__ char lds[];

  const int tid  = threadIdx.x;
  const int lane = tid & 63;
  const int wid  = tid >> 6;
  const int g16  = (lane >> 4) & 3;
  const int l15  = lane & 15;
  const int wm   = wid >> 2;
  const int wn   = wid & 3;

  const int nbn = N >> 8;
  const int wg  = (blockIdx.x & 7) * ((int)gridDim.x >> 3) + (blockIdx.x >> 3);
  const size_t bm = (size_t)(wg / nbn) << 8;
  const size_t bn = (size_t)(wg % nbn) << 8;

  const int NT = K >> 6;

  const int srow = tid >> 2;
  const int csel = (((tid & 3) ^ ((tid >> 3) & 3)) << 3);
  const int ldst = wid * 1024;
  const unsigned short* pA0 = A + (bm + srow) * (size_t)K + csel;
  const unsigned short* pA1 = pA0 + (size_t)128 * K;
  const unsigned short* pB0 = B + (bn + srow) * (size_t)K + csel;
  const unsigned short* pB1 = pB0 + (size_t)128 * K;

#define STAGE(p0, p1, kcol, regbase)                                   \
  do {                                                                 \
    GLOAD_LDS16((p0) + (kcol), lds + (regbase) + ldst);                \
    GLOAD_LDS16((p1) + (kcol), lds + (regbase) + 8192 + ldst);         \
  } while (0)

  const int s16  = ((g16 ^ ((l15 >> 1) & 3)) << 4);
  const int offA = (wm * 128 + l15) * 64 + s16;
  const int offB = (wn * 64 + l15) * 64 + s16;

  f32x4 acc[8][4];
  const f32x4 zero4 = {0.f, 0.f, 0.f, 0.f};
#pragma unroll
  for (int i = 0; i < 8; ++i)
#pragma unroll
    for (int j = 0; j < 4; ++j) acc[i][j] = zero4;

#define READ_A(par, kk, rh)                                              \
  { const char* rb = lds + (par) * 32768 + (kk) * 16384 + offA + (rh) * 4096; \
    af[0] = *(const bf16x8*)(rb);                                        \
    af[1] = *(const bf16x8*)(rb + 1024);                                 \
    af[2] = *(const bf16x8*)(rb + 2048);                                 \
    af[3] = *(const bf16x8*)(rb + 3072); }
#define READ_B(par, kk)                                                  \
  { const char* rb = lds + 65536 + (par) * 32768 + (kk) * 16384 + offB;  \
    bfv[0] = *(const bf16x8*)(rb);                                       \
    bfv[1] = *(const bf16x8*)(rb + 1024);                                \
    bfv[2] = *(const bf16x8*)(rb + 2048);                                \
    bfv[3] = *(const bf16x8*)(rb + 3072); }
#define MFMA16(rh)                                                       \
  _Pragma("unroll") for (int q = 0; q < 4; ++q)                          \
  _Pragma("unroll") for (int c = 0; c < 4; ++c)                          \
    acc[(rh) * 4 + q][c] = __builtin_amdgcn_mfma_f32_16x16x32_bf16(      \
        af[q], bfv[c], acc[(rh) * 4 + q][c], 0, 0, 0);
#define BAR() __builtin_amdgcn_s_barrier()
#define VMCNT8() asm volatile("s_waitcnt vmcnt(8)" ::: "memory")

  STAGE(pA0, pA1, 0, 0);
  STAGE(pB0, pB1, 0, 65536);
  STAGE(pA0, pA1, 32, 16384);
  STAGE(pB0, pB1, 32, 65536 + 16384);
  {
    const int k1 = (NT > 1 ? 64 : 0);
    STAGE(pA0, pA1, k1, 32768);
    STAGE(pB0, pB1, k1, 65536 + 32768);
  }
  VMCNT8();
  BAR();

  for (int t = 0; t < NT; ++t) {
    const int par  = t & 1;
    const int parn = par ^ 1;
    const int kc1  = (t + 1 < NT ? t + 1 : NT - 1) * 64;
    const int kc2  = (t + 2 < NT ? t + 2 : NT - 1) * 64;
    bf16x8 af[4], bfv[4];

    READ_A(par, 0, 0); READ_B(par, 0);
    STAGE(pA0, pA1, kc1 + 32, parn * 32768 + 16384);
    BAR();
    __builtin_amdgcn_s_setprio(1); MFMA16(0); __builtin_amdgcn_s_setprio(0);
    BAR();

    READ_A(par, 0, 1);
    STAGE(pB0, pB1, kc1 + 32, 65536 + parn * 32768 + 16384);
    VMCNT8();
    BAR();
    __builtin_amdgcn_s_setprio(1); MFMA16(1); __builtin_amdgcn_s_setprio(0);
    BAR();

    READ_A(par, 1, 0); READ_B(par, 1);
    STAGE(pA0, pA1, kc2, par * 32768);
    BAR();
    __builtin_amdgcn_s_setprio(1); MFMA16(0); __builtin_amdgcn_s_setprio(0);
    BAR();

    READ_A(par, 1, 1);
    STAGE(pB0, pB1, kc2, 65536 + par * 32768);
    VMCNT8();
    BAR();
    __builtin_amdgcn_s_setprio(1); MFMA16(1); __builtin_amdgcn_s_setprio(0);
    BAR();
  }

#pragma unroll
  for (int ai = 0; ai < 8; ++ai) {
    const size_t row0 = bm + wm * 128 + (ai >> 2) * 64 + (ai & 3) * 16 + g16 * 4;
#pragma unroll
    for (int c = 0; c < 4; ++c) {
      const size_t col = bn + wn * 64 + c * 16 + l15;
      const float bv = bias[col];
#pragma unroll
      for (int r = 0; r < 4; ++r) {
        const float v = acc[ai][c][r] + bv;
        const size_t idx = (row0 + r) * N + col;
        if (OUT_BF16) ((unsigned short*)Cout)[idx] = f2bf(v);
        else          ((float*)Cout)[idx] = v;
      }
    }
  }
#undef STAGE
#undef READ_A
#undef READ_B
#undef MFMA16
#undef BAR
#undef VMCNT8
}

// ---------------------------------------------------------------- fused mask-unit attention
// One block (256 thr, 4 waves) per (b,h,w). (R7-exact.)
__global__ __launch_bounds__(256) void attn_kernel(
    const unsigned short* __restrict__ qkv,   // [65536 x 2304] bf16
    float* __restrict__ attn_out,             // [b,h,w,64,256] fp32
    unsigned short* __restrict__ Xws) {       // [16384 x 768] bf16
  __shared__ unsigned short smem[32768];
  char* KP = (char*)smem;             // 32KB K region / later P region
  char* VT = (char*)(smem + 16384);   // 32KB V transposed [d][s]

  const int tid  = threadIdx.x;
  const int lane = tid & 63;
  const int wid  = tid >> 6;
  const int g16  = lane >> 4;
  const int l15  = lane & 15;

  const int bid = blockIdx.x;         // ((b*12 + h)*32 + w)
  const int w = bid & 31;
  const int h = (bid >> 5) % 12;
  const int b = bid / 384;

  const int s0 = tid >> 3;            // 0..31
  const int part = tid & 7;

#pragma unroll
  for (int p = 0; p < 8; ++p) {
    const int s = s0 + p * 32;
    const size_t gbase =
        ((size_t)b * 8192 + (size_t)s * 32 + w) * 2304 + h * 64 + part * 8;
    int4 kv = *(const int4*)(qkv + gbase + 768);
    *(int4*)(KP + ((s * 128 + part * 16) ^ ((s & 7) << 4))) = kv;
  }

#pragma unroll
  for (int p = 0; p < 2; ++p) {
    const int s = s0 * 4 + p * 128;
    const size_t gb0 =
        ((size_t)b * 8192 + (size_t)s * 32 + w) * 2304 + 1536 + h * 64 + part * 8;
    int4 x0 = *(const int4*)(qkv + gb0);
    int4 x1 = *(const int4*)(qkv + gb0 + 73728);
    int4 x2 = *(const int4*)(qkv + gb0 + 147456);
    int4 x3 = *(const int4*)(qkv + gb0 + 221184);
    const unsigned int* u0 = (const unsigned int*)&x0;
    const unsigned int* u1 = (const unsigned int*)&x1;
    const unsigned int* u2 = (const unsigned int*)&x2;
    const unsigned int* u3 = (const unsigned int*)&x3;
#pragma unroll
    for (int k = 0; k < 4; ++k) {
      const unsigned int lo01 = (u0[k] & 0xffffu) | (u1[k] << 16);
      const unsigned int lo23 = (u2[k] & 0xffffu) | (u3[k] << 16);
      const unsigned int hi01 = (u0[k] >> 16) | (u1[k] & 0xffff0000u);
      const unsigned int hi23 = (u2[k] >> 16) | (u3[k] & 0xffff0000u);
      const int dlo = part * 8 + 2 * k;
      const int dhi = dlo + 1;
      uint2 vlo; vlo.x = lo01; vlo.y = lo23;
      uint2 vhi; vhi.x = hi01; vhi.y = hi23;
      *(uint2*)(VT + ((dlo * 512 + s * 2) ^ ((dlo & 7) << 4))) = vlo;
      *(uint2*)(VT + ((dhi * 512 + s * 2) ^ ((dhi & 7) << 4))) = vhi;
    }
  }

  union BU { unsigned short u[8]; bf16x8 v; };
  BU aq0, aq1;
  {
    const int qrow = wid * 16 + l15;
    float q0[8], q1[8];
#pragma unroll
    for (int j = 0; j < 8; ++j) { q0[j] = -1e30f; q1[j] = -1e30f; }
#pragma unroll
    for (int g = 0; g < 4; ++g) {
      const size_t gbase =
          ((size_t)b * 8192 + (size_t)(g * 64 + qrow) * 32 + w) * 2304 +
          h * 64 + g16 * 8;
      int4 a = *(const int4*)(qkv + gbase);
      int4 c = *(const int4*)(qkv + gbase + 32);
      const unsigned short* pa = (const unsigned short*)&a;
      const unsigned short* pc = (const unsigned short*)&c;
#pragma unroll
      for (int j = 0; j < 8; ++j) {
        q0[j] = fmaxf(q0[j], bf2f(pa[j]));
        q1[j] = fmaxf(q1[j], bf2f(pc[j]));
      }
    }
#pragma unroll
    for (int j = 0; j < 8; ++j) {
      aq0.u[j] = (unsigned short)(__float_as_uint(q0[j]) >> 16);
      aq1.u[j] = (unsigned short)(__float_as_uint(q1[j]) >> 16);
    }
  }

  __syncthreads();

  f32x4 sacc[16];
  const f32x4 zero4 = {0.f, 0.f, 0.f, 0.f};
#pragma unroll
  for (int t = 0; t < 16; ++t) sacc[t] = zero4;
#pragma unroll
  for (int t = 0; t < 16; ++t) {
    const int srow = t * 16 + l15;
    bf16x8 bk0 = *(const bf16x8*)(KP + ((srow * 128 + 0  + g16 * 16) ^ ((srow & 7) << 4)));
    bf16x8 bk1 = *(const bf16x8*)(KP + ((srow * 128 + 64 + g16 * 16) ^ ((srow & 7) << 4)));
    sacc[t] = __builtin_amdgcn_mfma_f32_16x16x32_bf16(aq0.v, bk0, sacc[t], 0, 0, 0);
    sacc[t] = __builtin_amdgcn_mfma_f32_16x16x32_bf16(aq1.v, bk1, sacc[t], 0, 0, 0);
  }

  float inv_[4];
#pragma unroll
  for (int r = 0; r < 4; ++r) {
    float m = -1e30f;
#pragma unroll
    for (int t = 0; t < 16; ++t) { sacc[t][r] *= 0.125f; m = fmaxf(m, sacc[t][r]); }
#pragma unroll
    for (int off = 1; off < 16; off <<= 1) m = fmaxf(m, __shfl_xor(m, off, 64));
    float ssum = 0.f;
#pragma unroll
    for (int t = 0; t < 16; ++t) {
      float e = expf(sacc[t][r] - m);
      sacc[t][r] = e;
      ssum += e;
    }
#pragma unroll
    for (int off = 1; off < 16; off <<= 1) ssum += __shfl_xor(ssum, off, 64);
    inv_[r] = 1.f / ssum;
  }

  {
    float* ab = attn_out + ((size_t)bid * 64 + wid * 16) * 256;
#pragma unroll
    for (int t = 0; t < 16; ++t)
#pragma unroll
      for (int r = 0; r < 4; ++r) {
        const float p = sacc[t][r] * inv_[r];
        sacc[t][r] = p;
        ab[(size_t)(g16 * 4 + r) * 256 + t * 16 + l15] = p;
      }
  }

  __syncthreads();

  {
    char* PW = KP + wid * 8192;
#pragma unroll
    for (int t = 0; t < 16; ++t)
#pragma unroll
      for (int r = 0; r < 4; ++r) {
        const int row = g16 * 4 + r;
        *(unsigned short*)(PW + ((row * 512 + (t * 16 + l15) * 2) ^ ((row & 7) << 4))) =
            f2bf(sacc[t][r]);
      }
  }

  f32x4 oacc[4];
#pragma unroll
  for (int n = 0; n < 4; ++n) oacc[n] = zero4;
  {
    const char* PR = KP + wid * 8192;
#pragma unroll
    for (int kc = 0; kc < 8; ++kc) {
      bf16x8 pa = *(const bf16x8*)(PR + ((l15 * 512 + kc * 64 + g16 * 16) ^ ((l15 & 7) << 4)));
#pragma unroll
      for (int n = 0; n < 4; ++n) {
        const int d = n * 16 + l15;
        bf16x8 vv = *(const bf16x8*)(VT + ((d * 512 + kc * 64 + g16 * 16) ^ ((d & 7) << 4)));
        oacc[n] = __builtin_amdgcn_mfma_f32_16x16x32_bf16(pa, vv, oacc[n], 0, 0, 0);
      }
    }
  }

#pragma unroll
  for (int n = 0; n < 4; ++n)
#pragma unroll
    for (int r = 0; r < 4; ++r) {
      const int qi = wid * 16 + g16 * 4 + r;
      Xws[((size_t)b * 2048 + qi * 32 + w) * 768 + h * 64 + n * 16 + l15] =
          f2bf(oacc[n][r]);
    }
}

// ---------------------------------------------------------------- launch
extern "C" void kernel_launch(void* const* d_in, const int* in_sizes, int n_in,
                              void* d_out, int out_size, void* d_ws, size_t ws_size,
                              hipStream_t stream) {
  const float* emb    = (const float*)d_in[0];
  const float* qkv_w  = (const float*)d_in[1];
  const float* qkv_b  = (const float*)d_in[2];
  const float* proj_w = (const float*)d_in[3];
  const float* proj_b = (const float*)d_in[4];
  float* out = (float*)d_out;

  char* ws = (char*)d_ws;
  unsigned short* wqkvB  = (unsigned short*)(ws + 100663296);
  unsigned short* wprojB = (unsigned short*)(ws + 104202240);
  unsigned short* qkvB   = (unsigned short*)(ws + 105381888);
  unsigned short* Xws    = (unsigned short*)(ws + 407371776);

  // 1) weight fp32 -> bf16 (embeddings cvt fused into GEMM A-staging)
  cvt_w2<<<2048, 256, 0, stream>>>(qkv_w, wqkvB, 1769472 / 4,
                                   proj_w, wprojB, 589824 / 4);

  // 2) qkv = emb(fp32) @ qkv_w^T + qkv_b  (bf16 out; fused-cvt DMA staging)
  hipFuncSetAttribute(reinterpret_cast<const void*>(&gemmf32a<1>),
                      hipFuncAttributeMaxDynamicSharedMemorySize, 131072);
  gemmf32a<1><<<4608, 512, 131072, stream>>>(emb, wqkvB, qkv_b, qkvB,
                                             65536, 2304, 768);

  // 3) fused mask-unit attention (attn fp32 to d_out tail, X bf16 to ws)
  attn_kernel<<<3072, 256, 0, stream>>>(qkvB, out + 12582912, Xws);

  // 4) out = X @ proj_w^T + proj_b  (fp32 out; 256^2 per-tile, 192 blocks)
  hipFuncSetAttribute(reinterpret_cast<const void*>(&gemm256t<0>),
                      hipFuncAttributeMaxDynamicSharedMemorySize, 131072);
  gemm256t<0><<<192, 512, 131072, stream>>>(Xws, wprojB, proj_b, out,
                                            16384, 768, 768);
}

// Round 11
// 482.128 us; speedup vs baseline: 1.1916x; 1.1916x over previous
//
#include <hip/hip_runtime.h>
#include <hip/hip_bf16.h>

// HieraMaskUnitAttention on MI355X (gfx950).
// B=8 T=8192 D=768 H=12 HD=64 Q_STRIDE=4 WINDOW=64 -> nw=32, seq=256, q_len=64
//
// Pipeline (R11 = R9 + single merged cvt):
//   1) cvt_all: embeddings + qkv_w + proj_w fp32->bf16 in ONE launch
//   2) gemm256p<bf16 out>: qkv = emb @ qkv_w^T + qkv_b  (persistent 256 blocks)
//   3) attn_kernel (R7): Q max-pool, QK^T softmax (attn fp32 -> d_out), PV -> X ws
//   4) gemm256t<f32 out>: out = X @ proj_w^T + proj_b (256^2 per-tile, 192 blocks)
//
// CLOSED BRANCHES (measured): cvt-fusion into GEMM (R6: persistent fp32-A L3
// blowout FETCH 902MB; R8: reg-staged A exposes HBM latency, MfmaUtil 21%;
// R10: BM128 2-phase + fp32-A DMA -> bank conflicts 4.2e7, MfmaUtil 21%).
// GEMM micro-schedule variants (R3-R5: per-tile/persistent/±sched_barrier/
// early-read all pin at MfmaUtil ~37% / ~845 TF — this structure's plateau).

typedef float  f32x4  __attribute__((ext_vector_type(4)));
typedef __bf16 bf16x8 __attribute__((ext_vector_type(8)));

__device__ __forceinline__ unsigned short f2bf(float f) {
  unsigned int u = __float_as_uint(f);
  u += 0x7fffu + ((u >> 16) & 1u);      // RNE
  return (unsigned short)(u >> 16);
}
__device__ __forceinline__ float bf2f(unsigned short b) {
  return __uint_as_float(((unsigned int)b) << 16);
}

#define GLOAD_LDS16(gptr, lptr) __builtin_amdgcn_global_load_lds( \
    (const __attribute__((address_space(1))) void*)(gptr),        \
    (__attribute__((address_space(3))) void*)(lptr), 16, 0, 0)

// ---------------------------------------------------------------- merged cvt fp32->bf16
// Three tensors in one grid-stride launch (all pure HBM-bound).
__global__ void cvt_all(const float* __restrict__ s0, unsigned short* __restrict__ d0,
                        int n0,
                        const float* __restrict__ s1, unsigned short* __restrict__ d1,
                        int n1,
                        const float* __restrict__ s2, unsigned short* __restrict__ d2,
                        int n2) {
  int i = blockIdx.x * blockDim.x + threadIdx.x;
  const int stride = gridDim.x * blockDim.x;
  const int tot = n0 + n1 + n2;
  for (; i < tot; i += stride) {
    const float* s;
    unsigned short* d;
    int j = i;
    if (j < n0)            { s = s0; d = d0; }
    else if ((j -= n0) < n1) { s = s1; d = d1; }
    else                   { j -= n1; s = s2; d = d2; }
    const float4 v = ((const float4*)s)[j];
    ushort4 o;
    o.x = f2bf(v.x); o.y = f2bf(v.y); o.z = f2bf(v.z); o.w = f2bf(v.w);
    ((ushort4*)d)[j] = o;
  }
}

// ---------------------------------------------------------------- persistent 256x256 GEMM
// C = A @ B^T + bias. A: [M x K] bf16 K-fast, B: [N x K] bf16 K-fast. (R4/R9-exact)
// grid = M/256 blocks, 1/CU (128KB LDS). K-stream step s over n-tiles j.
// LDS regions: A(par,kh)=par*32768+kh*16384, B=+65536; par = s&1.
//   ph1 stage A-Kh1(s+1)   ph2 stage B-Kh1(s+1), vmcnt(8)
//   ph3 stage A-Kh0(s+2)   ph4 stage B-Kh0(s+2), vmcnt(8)
// Swizzle: byte p ^= ((p>>7)&3)<<4 pre-applied on global source, applied on reads.
template <int OUT_BF16>
__global__ __launch_bounds__(512, 2) void gemm256p(
    const unsigned short* __restrict__ A, const unsigned short* __restrict__ B,
    const float* __restrict__ bias, void* __restrict__ Cout,
    int M, int N, int K) {
  extern __shared__ char lds[];

  const int tid  = threadIdx.x;
  const int lane = tid & 63;
  const int wid  = tid >> 6;
  const int g16  = (lane >> 4) & 3;
  const int l15  = lane & 15;
  const int wm   = wid >> 2;
  const int wn   = wid & 3;

  const size_t bm = (size_t)blockIdx.x << 8;
  const int NT = K >> 6;
  const int NB = N >> 8;
  const int TT = NB * NT;

  const int srow = tid >> 2;
  const int csel = (((tid & 3) ^ ((tid >> 3) & 3)) << 3);
  const int ldst = wid * 1024;
  const unsigned short* pA0 = A + (bm + srow) * (size_t)K + csel;
  const unsigned short* pA1 = pA0 + (size_t)128 * K;
  const unsigned short* pB0 = B + (size_t)srow * K + csel;
  const unsigned short* pB1 = pB0 + (size_t)128 * K;

#define STAGE_A(koff, regbase)                                          \
  do {                                                                  \
    GLOAD_LDS16(pA0 + (koff), lds + (regbase) + ldst);                  \
    GLOAD_LDS16(pA1 + (koff), lds + (regbase) + 8192 + ldst);           \
  } while (0)
#define STAGE_B(boff, regbase)                                          \
  do {                                                                  \
    GLOAD_LDS16(pB0 + (boff), lds + (regbase) + ldst);                  \
    GLOAD_LDS16(pB1 + (boff), lds + (regbase) + 8192 + ldst);           \
  } while (0)

  const int s16  = ((g16 ^ ((l15 >> 1) & 3)) << 4);
  const int offA = (wm * 128 + l15) * 64 + s16;
  const int offB = (wn * 64 + l15) * 64 + s16;

  f32x4 acc[8][4];
  const f32x4 zero4 = {0.f, 0.f, 0.f, 0.f};
#pragma unroll
  for (int i = 0; i < 8; ++i)
#pragma unroll
    for (int j = 0; j < 4; ++j) acc[i][j] = zero4;

#define READ_A(par, kk, rh)                                              \
  { const char* rb = lds + (par) * 32768 + (kk) * 16384 + offA + (rh) * 4096; \
    af[0] = *(const bf16x8*)(rb);                                        \
    af[1] = *(const bf16x8*)(rb + 1024);                                 \
    af[2] = *(const bf16x8*)(rb + 2048);                                 \
    af[3] = *(const bf16x8*)(rb + 3072); }
#define READ_B(par, kk)                                                  \
  { const char* rb = lds + 65536 + (par) * 32768 + (kk) * 16384 + offB;  \
    bfv[0] = *(const bf16x8*)(rb);                                       \
    bfv[1] = *(const bf16x8*)(rb + 1024);                                \
    bfv[2] = *(const bf16x8*)(rb + 2048);                                \
    bfv[3] = *(const bf16x8*)(rb + 3072); }
#define MFMA16(rh)                                                       \
  _Pragma("unroll") for (int q = 0; q < 4; ++q)                          \
  _Pragma("unroll") for (int c = 0; c < 4; ++c)                          \
    acc[(rh) * 4 + q][c] = __builtin_amdgcn_mfma_f32_16x16x32_bf16(      \
        af[q], bfv[c], acc[(rh) * 4 + q][c], 0, 0, 0);
#define BAR() __builtin_amdgcn_s_barrier()
#define VMCNT8() asm volatile("s_waitcnt vmcnt(8)" ::: "memory")

  int    kk  = 0;
  int    bnC = 0;
  int    k1  = 64;
  int    k2  = 128;
  size_t rB1 = 0;
  size_t rB2 = 0;

  STAGE_A(0, 0);
  STAGE_B(0, 65536);
  STAGE_A(32, 16384);
  STAGE_B(32, 65536 + 16384);
  STAGE_A(64, 32768);
  STAGE_B(64, 65536 + 32768);
  VMCNT8();
  BAR();

  for (int s = 0; s < TT; ++s) {
    const int par  = s & 1;
    const int parn = par ^ 1;
    bf16x8 af[4], bfv[4];

    READ_A(par, 0, 0); READ_B(par, 0);
    STAGE_A(k1 + 32, parn * 32768 + 16384);
    BAR();
    __builtin_amdgcn_s_setprio(1); MFMA16(0); __builtin_amdgcn_s_setprio(0);
    BAR();

    READ_A(par, 0, 1);
    STAGE_B(rB1 + k1 + 32, 65536 + parn * 32768 + 16384);
    VMCNT8();
    BAR();
    __builtin_amdgcn_s_setprio(1); MFMA16(1); __builtin_amdgcn_s_setprio(0);
    BAR();

    READ_A(par, 1, 0); READ_B(par, 1);
    STAGE_A(k2, par * 32768);
    BAR();
    __builtin_amdgcn_s_setprio(1); MFMA16(0); __builtin_amdgcn_s_setprio(0);
    BAR();

    READ_A(par, 1, 1);
    STAGE_B(rB2 + k2, 65536 + par * 32768);
    VMCNT8();
    BAR();
    __builtin_amdgcn_s_setprio(1); MFMA16(1); __builtin_amdgcn_s_setprio(0);
    BAR();

    if (kk == NT - 1) {
#pragma unroll
      for (int ai = 0; ai < 8; ++ai) {
        const size_t row0 =
            bm + wm * 128 + (ai >> 2) * 64 + (ai & 3) * 16 + g16 * 4;
#pragma unroll
        for (int c = 0; c < 4; ++c) {
          const int col = bnC + wn * 64 + c * 16 + l15;
          const float bv = bias[col];
#pragma unroll
          for (int r = 0; r < 4; ++r) {
            const float v = acc[ai][c][r] + bv;
            const size_t idx = (row0 + r) * (size_t)N + col;
            if (OUT_BF16) ((unsigned short*)Cout)[idx] = f2bf(v);
            else          ((float*)Cout)[idx] = v;
          }
          acc[ai][c] = zero4;
        }
      }
      bnC += 256;
      kk = 0;
    } else {
      ++kk;
    }

    k1 = k2; rB1 = rB2;
    if (s + 3 < TT) {
      k2 += 64;
      if (k2 == K) { k2 = 0; rB2 += (size_t)256 * K; }
    }
  }
#undef STAGE_A
#undef STAGE_B
#undef READ_A
#undef READ_B
#undef MFMA16
#undef BAR
#undef VMCNT8
}

// ---------------------------------------------------------------- per-tile 256x256 GEMM
// C = A @ B^T + bias, both bf16 K-fast. (R9 proj kernel, unchanged.)
template <int OUT_BF16>
__global__ __launch_bounds__(512, 2) void gemm256t(
    const unsigned short* __restrict__ A, const unsigned short* __restrict__ B,
    const float* __restrict__ bias, void* __restrict__ Cout,
    int M, int N, int K) {
  extern __shared__ char lds[];

  const int tid  = threadIdx.x;
  const int lane = tid & 63;
  const int wid  = tid >> 6;
  const int g16  = (lane >> 4) & 3;
  const int l15  = lane & 15;
  const int wm   = wid >> 2;
  const int wn   = wid & 3;

  const int nbn = N >> 8;
  const int wg  = (blockIdx.x & 7) * ((int)gridDim.x >> 3) + (blockIdx.x >> 3);
  const size_t bm = (size_t)(wg / nbn) << 8;
  const size_t bn = (size_t)(wg % nbn) << 8;

  const int NT = K >> 6;

  const int srow = tid >> 2;
  const int csel = (((tid & 3) ^ ((tid >> 3) & 3)) << 3);
  const int ldst = wid * 1024;
  const unsigned short* pA0 = A + (bm + srow) * (size_t)K + csel;
  const unsigned short* pA1 = pA0 + (size_t)128 * K;
  const unsigned short* pB0 = B + (bn + srow) * (size_t)K + csel;
  const unsigned short* pB1 = pB0 + (size_t)128 * K;

#define STAGE(p0, p1, kcol, regbase)                                   \
  do {                                                                 \
    GLOAD_LDS16((p0) + (kcol), lds + (regbase) + ldst);                \
    GLOAD_LDS16((p1) + (kcol), lds + (regbase) + 8192 + ldst);         \
  } while (0)

  const int s16  = ((g16 ^ ((l15 >> 1) & 3)) << 4);
  const int offA = (wm * 128 + l15) * 64 + s16;
  const int offB = (wn * 64 + l15) * 64 + s16;

  f32x4 acc[8][4];
  const f32x4 zero4 = {0.f, 0.f, 0.f, 0.f};
#pragma unroll
  for (int i = 0; i < 8; ++i)
#pragma unroll
    for (int j = 0; j < 4; ++j) acc[i][j] = zero4;

#define READ_A(par, kk, rh)                                              \
  { const char* rb = lds + (par) * 32768 + (kk) * 16384 + offA + (rh) * 4096; \
    af[0] = *(const bf16x8*)(rb);                                        \
    af[1] = *(const bf16x8*)(rb + 1024);                                 \
    af[2] = *(const bf16x8*)(rb + 2048);                                 \
    af[3] = *(const bf16x8*)(rb + 3072); }
#define READ_B(par, kk)                                                  \
  { const char* rb = lds + 65536 + (par) * 32768 + (kk) * 16384 + offB;  \
    bfv[0] = *(const bf16x8*)(rb);                                       \
    bfv[1] = *(const bf16x8*)(rb + 1024);                                \
    bfv[2] = *(const bf16x8*)(rb + 2048);                                \
    bfv[3] = *(const bf16x8*)(rb + 3072); }
#define MFMA16(rh)                                                       \
  _Pragma("unroll") for (int q = 0; q < 4; ++q)                          \
  _Pragma("unroll") for (int c = 0; c < 4; ++c)                          \
    acc[(rh) * 4 + q][c] = __builtin_amdgcn_mfma_f32_16x16x32_bf16(      \
        af[q], bfv[c], acc[(rh) * 4 + q][c], 0, 0, 0);
#define BAR() __builtin_amdgcn_s_barrier()
#define VMCNT8() asm volatile("s_waitcnt vmcnt(8)" ::: "memory")

  STAGE(pA0, pA1, 0, 0);
  STAGE(pB0, pB1, 0, 65536);
  STAGE(pA0, pA1, 32, 16384);
  STAGE(pB0, pB1, 32, 65536 + 16384);
  {
    const int k1 = (NT > 1 ? 64 : 0);
    STAGE(pA0, pA1, k1, 32768);
    STAGE(pB0, pB1, k1, 65536 + 32768);
  }
  VMCNT8();
  BAR();

  for (int t = 0; t < NT; ++t) {
    const int par  = t & 1;
    const int parn = par ^ 1;
    const int kc1  = (t + 1 < NT ? t + 1 : NT - 1) * 64;
    const int kc2  = (t + 2 < NT ? t + 2 : NT - 1) * 64;
    bf16x8 af[4], bfv[4];

    READ_A(par, 0, 0); READ_B(par, 0);
    STAGE(pA0, pA1, kc1 + 32, parn * 32768 + 16384);
    BAR();
    __builtin_amdgcn_s_setprio(1); MFMA16(0); __builtin_amdgcn_s_setprio(0);
    BAR();

    READ_A(par, 0, 1);
    STAGE(pB0, pB1, kc1 + 32, 65536 + parn * 32768 + 16384);
    VMCNT8();
    BAR();
    __builtin_amdgcn_s_setprio(1); MFMA16(1); __builtin_amdgcn_s_setprio(0);
    BAR();

    READ_A(par, 1, 0); READ_B(par, 1);
    STAGE(pA0, pA1, kc2, par * 32768);
    BAR();
    __builtin_amdgcn_s_setprio(1); MFMA16(0); __builtin_amdgcn_s_setprio(0);
    BAR();

    READ_A(par, 1, 1);
    STAGE(pB0, pB1, kc2, 65536 + par * 32768);
    VMCNT8();
    BAR();
    __builtin_amdgcn_s_setprio(1); MFMA16(1); __builtin_amdgcn_s_setprio(0);
    BAR();
  }

#pragma unroll
  for (int ai = 0; ai < 8; ++ai) {
    const size_t row0 = bm + wm * 128 + (ai >> 2) * 64 + (ai & 3) * 16 + g16 * 4;
#pragma unroll
    for (int c = 0; c < 4; ++c) {
      const size_t col = bn + wn * 64 + c * 16 + l15;
      const float bv = bias[col];
#pragma unroll
      for (int r = 0; r < 4; ++r) {
        const float v = acc[ai][c][r] + bv;
        const size_t idx = (row0 + r) * N + col;
        if (OUT_BF16) ((unsigned short*)Cout)[idx] = f2bf(v);
        else          ((float*)Cout)[idx] = v;
      }
    }
  }
#undef STAGE
#undef READ_A
#undef READ_B
#undef MFMA16
#undef BAR
#undef VMCNT8
}

// ---------------------------------------------------------------- fused mask-unit attention
// One block (256 thr, 4 waves) per (b,h,w). (R7-exact.)
__global__ __launch_bounds__(256) void attn_kernel(
    const unsigned short* __restrict__ qkv,   // [65536 x 2304] bf16
    float* __restrict__ attn_out,             // [b,h,w,64,256] fp32
    unsigned short* __restrict__ Xws) {       // [16384 x 768] bf16
  __shared__ unsigned short smem[32768];
  char* KP = (char*)smem;             // 32KB K region / later P region
  char* VT = (char*)(smem + 16384);   // 32KB V transposed [d][s]

  const int tid  = threadIdx.x;
  const int lane = tid & 63;
  const int wid  = tid >> 6;
  const int g16  = lane >> 4;
  const int l15  = lane & 15;

  const int bid = blockIdx.x;         // ((b*12 + h)*32 + w)
  const int w = bid & 31;
  const int h = (bid >> 5) % 12;
  const int b = bid / 384;

  const int s0 = tid >> 3;            // 0..31
  const int part = tid & 7;

#pragma unroll
  for (int p = 0; p < 8; ++p) {
    const int s = s0 + p * 32;
    const size_t gbase =
        ((size_t)b * 8192 + (size_t)s * 32 + w) * 2304 + h * 64 + part * 8;
    int4 kv = *(const int4*)(qkv + gbase + 768);
    *(int4*)(KP + ((s * 128 + part * 16) ^ ((s & 7) << 4))) = kv;
  }

#pragma unroll
  for (int p = 0; p < 2; ++p) {
    const int s = s0 * 4 + p * 128;
    const size_t gb0 =
        ((size_t)b * 8192 + (size_t)s * 32 + w) * 2304 + 1536 + h * 64 + part * 8;
    int4 x0 = *(const int4*)(qkv + gb0);
    int4 x1 = *(const int4*)(qkv + gb0 + 73728);
    int4 x2 = *(const int4*)(qkv + gb0 + 147456);
    int4 x3 = *(const int4*)(qkv + gb0 + 221184);
    const unsigned int* u0 = (const unsigned int*)&x0;
    const unsigned int* u1 = (const unsigned int*)&x1;
    const unsigned int* u2 = (const unsigned int*)&x2;
    const unsigned int* u3 = (const unsigned int*)&x3;
#pragma unroll
    for (int k = 0; k < 4; ++k) {
      const unsigned int lo01 = (u0[k] & 0xffffu) | (u1[k] << 16);
      const unsigned int lo23 = (u2[k] & 0xffffu) | (u3[k] << 16);
      const unsigned int hi01 = (u0[k] >> 16) | (u1[k] & 0xffff0000u);
      const unsigned int hi23 = (u2[k] >> 16) | (u3[k] & 0xffff0000u);
      const int dlo = part * 8 + 2 * k;
      const int dhi = dlo + 1;
      uint2 vlo; vlo.x = lo01; vlo.y = lo23;
      uint2 vhi; vhi.x = hi01; vhi.y = hi23;
      *(uint2*)(VT + ((dlo * 512 + s * 2) ^ ((dlo & 7) << 4))) = vlo;
      *(uint2*)(VT + ((dhi * 512 + s * 2) ^ ((dhi & 7) << 4))) = vhi;
    }
  }

  union BU { unsigned short u[8]; bf16x8 v; };
  BU aq0, aq1;
  {
    const int qrow = wid * 16 + l15;
    float q0[8], q1[8];
#pragma unroll
    for (int j = 0; j < 8; ++j) { q0[j] = -1e30f; q1[j] = -1e30f; }
#pragma unroll
    for (int g = 0; g < 4; ++g) {
      const size_t gbase =
          ((size_t)b * 8192 + (size_t)(g * 64 + qrow) * 32 + w) * 2304 +
          h * 64 + g16 * 8;
      int4 a = *(const int4*)(qkv + gbase);
      int4 c = *(const int4*)(qkv + gbase + 32);
      const unsigned short* pa = (const unsigned short*)&a;
      const unsigned short* pc = (const unsigned short*)&c;
#pragma unroll
      for (int j = 0; j < 8; ++j) {
        q0[j] = fmaxf(q0[j], bf2f(pa[j]));
        q1[j] = fmaxf(q1[j], bf2f(pc[j]));
      }
    }
#pragma unroll
    for (int j = 0; j < 8; ++j) {
      aq0.u[j] = (unsigned short)(__float_as_uint(q0[j]) >> 16);
      aq1.u[j] = (unsigned short)(__float_as_uint(q1[j]) >> 16);
    }
  }

  __syncthreads();

  f32x4 sacc[16];
  const f32x4 zero4 = {0.f, 0.f, 0.f, 0.f};
#pragma unroll
  for (int t = 0; t < 16; ++t) sacc[t] = zero4;
#pragma unroll
  for (int t = 0; t < 16; ++t) {
    const int srow = t * 16 + l15;
    bf16x8 bk0 = *(const bf16x8*)(KP + ((srow * 128 + 0  + g16 * 16) ^ ((srow & 7) << 4)));
    bf16x8 bk1 = *(const bf16x8*)(KP + ((srow * 128 + 64 + g16 * 16) ^ ((srow & 7) << 4)));
    sacc[t] = __builtin_amdgcn_mfma_f32_16x16x32_bf16(aq0.v, bk0, sacc[t], 0, 0, 0);
    sacc[t] = __builtin_amdgcn_mfma_f32_16x16x32_bf16(aq1.v, bk1, sacc[t], 0, 0, 0);
  }

  float inv_[4];
#pragma unroll
  for (int r = 0; r < 4; ++r) {
    float m = -1e30f;
#pragma unroll
    for (int t = 0; t < 16; ++t) { sacc[t][r] *= 0.125f; m = fmaxf(m, sacc[t][r]); }
#pragma unroll
    for (int off = 1; off < 16; off <<= 1) m = fmaxf(m, __shfl_xor(m, off, 64));
    float ssum = 0.f;
#pragma unroll
    for (int t = 0; t < 16; ++t) {
      float e = expf(sacc[t][r] - m);
      sacc[t][r] = e;
      ssum += e;
    }
#pragma unroll
    for (int off = 1; off < 16; off <<= 1) ssum += __shfl_xor(ssum, off, 64);
    inv_[r] = 1.f / ssum;
  }

  {
    float* ab = attn_out + ((size_t)bid * 64 + wid * 16) * 256;
#pragma unroll
    for (int t = 0; t < 16; ++t)
#pragma unroll
      for (int r = 0; r < 4; ++r) {
        const float p = sacc[t][r] * inv_[r];
        sacc[t][r] = p;
        ab[(size_t)(g16 * 4 + r) * 256 + t * 16 + l15] = p;
      }
  }

  __syncthreads();

  {
    char* PW = KP + wid * 8192;
#pragma unroll
    for (int t = 0; t < 16; ++t)
#pragma unroll
      for (int r = 0; r < 4; ++r) {
        const int row = g16 * 4 + r;
        *(unsigned short*)(PW + ((row * 512 + (t * 16 + l15) * 2) ^ ((row & 7) << 4))) =
            f2bf(sacc[t][r]);
      }
  }

  f32x4 oacc[4];
#pragma unroll
  for (int n = 0; n < 4; ++n) oacc[n] = zero4;
  {
    const char* PR = KP + wid * 8192;
#pragma unroll
    for (int kc = 0; kc < 8; ++kc) {
      bf16x8 pa = *(const bf16x8*)(PR + ((l15 * 512 + kc * 64 + g16 * 16) ^ ((l15 & 7) << 4)));
#pragma unroll
      for (int n = 0; n < 4; ++n) {
        const int d = n * 16 + l15;
        bf16x8 vv = *(const bf16x8*)(VT + ((d * 512 + kc * 64 + g16 * 16) ^ ((d & 7) << 4)));
        oacc[n] = __builtin_amdgcn_mfma_f32_16x16x32_bf16(pa, vv, oacc[n], 0, 0, 0);
      }
    }
  }

#pragma unroll
  for (int n = 0; n < 4; ++n)
#pragma unroll
    for (int r = 0; r < 4; ++r) {
      const int qi = wid * 16 + g16 * 4 + r;
      Xws[((size_t)b * 2048 + qi * 32 + w) * 768 + h * 64 + n * 16 + l15] =
          f2bf(oacc[n][r]);
    }
}

// ---------------------------------------------------------------- launch
extern "C" void kernel_launch(void* const* d_in, const int* in_sizes, int n_in,
                              void* d_out, int out_size, void* d_ws, size_t ws_size,
                              hipStream_t stream) {
  const float* emb    = (const float*)d_in[0];
  const float* qkv_w  = (const float*)d_in[1];
  const float* qkv_b  = (const float*)d_in[2];
  const float* proj_w = (const float*)d_in[3];
  const float* proj_b = (const float*)d_in[4];
  float* out = (float*)d_out;

  char* ws = (char*)d_ws;
  unsigned short* embB   = (unsigned short*)(ws);
  unsigned short* wqkvB  = (unsigned short*)(ws + 100663296);
  unsigned short* wprojB = (unsigned short*)(ws + 104202240);
  unsigned short* qkvB   = (unsigned short*)(ws + 105381888);
  unsigned short* Xws    = (unsigned short*)(ws + 407371776);

  // 1) all fp32 -> bf16 conversions in one launch
  cvt_all<<<4096, 256, 0, stream>>>(emb, embB, 50331648 / 4,
                                    qkv_w, wqkvB, 1769472 / 4,
                                    proj_w, wprojB, 589824 / 4);

  // 2) qkv = emb @ qkv_w^T + qkv_b  (bf16 out; persistent 256^2, 128KB dyn LDS)
  hipFuncSetAttribute(reinterpret_cast<const void*>(&gemm256p<1>),
                      hipFuncAttributeMaxDynamicSharedMemorySize, 131072);
  gemm256p<1><<<256, 512, 131072, stream>>>(embB, wqkvB, qkv_b, qkvB,
                                            65536, 2304, 768);

  // 3) fused mask-unit attention (attn fp32 to d_out tail, X bf16 to ws)
  attn_kernel<<<3072, 256, 0, stream>>>(qkvB, out + 12582912, Xws);

  // 4) out = X @ proj_w^T + proj_b  (fp32 out; 256^2 per-tile, 192 blocks)
  hipFuncSetAttribute(reinterpret_cast<const void*>(&gemm256t<0>),
                      hipFuncAttributeMaxDynamicSharedMemorySize, 131072);
  gemm256t<0><<<192, 512, 131072, stream>>>(Xws, wprojB, proj_b, out,
                                            16384, 768, 768);
}

// Round 12
// 463.871 us; speedup vs baseline: 1.2385x; 1.0394x over previous
//
#include <hip/hip_runtime.h>
#include <hip/hip_bf16.h>

// HieraMaskUnitAttention on MI355X (gfx950).
// B=8 T=8192 D=768 H=12 HD=64 Q_STRIDE=4 WINDOW=64 -> nw=32, seq=256, q_len=64
//
// Pipeline (R12 = R9-exact, best measured config: 465.5 us):
//   1) cvt_bf16: embeddings; cvt_w2: qkv_w + proj_w in ONE launch
//   2) gemm256p<bf16 out>: qkv = emb @ qkv_w^T + qkv_b  (persistent 256 blocks)
//   3) attn_kernel (R7): Q max-pool, QK^T softmax (attn fp32 -> d_out), PV -> X ws
//   4) gemm256t<f32 out>: out = X @ proj_w^T + proj_b (256^2 per-tile, 192 blocks)
//
// CLOSED BRANCHES (measured): cvt-fusion into GEMM (R6: persistent fp32-A L3
// blowout; R8: reg-staged A latency; R10: BM128 2-phase bank conflicts).
// GEMM micro-schedule variants (R3-R5) all pin at MfmaUtil ~37% / ~845 TF.
// R11 cvt-merge: wash within environment noise (gemm code identical, ran +7%).

typedef float  f32x4  __attribute__((ext_vector_type(4)));
typedef __bf16 bf16x8 __attribute__((ext_vector_type(8)));

__device__ __forceinline__ unsigned short f2bf(float f) {
  unsigned int u = __float_as_uint(f);
  u += 0x7fffu + ((u >> 16) & 1u);      // RNE
  return (unsigned short)(u >> 16);
}
__device__ __forceinline__ float bf2f(unsigned short b) {
  return __uint_as_float(((unsigned int)b) << 16);
}

#define GLOAD_LDS16(gptr, lptr) __builtin_amdgcn_global_load_lds( \
    (const __attribute__((address_space(1))) void*)(gptr),        \
    (__attribute__((address_space(3))) void*)(lptr), 16, 0, 0)

// ---------------------------------------------------------------- cvt fp32->bf16
__global__ void cvt_bf16(const float* __restrict__ src,
                         unsigned short* __restrict__ dst, int n4) {
  int i = blockIdx.x * blockDim.x + threadIdx.x;
  const int stride = gridDim.x * blockDim.x;
  for (; i < n4; i += stride) {
    const float4 v = ((const float4*)src)[i];
    ushort4 o;
    o.x = f2bf(v.x); o.y = f2bf(v.y); o.z = f2bf(v.z); o.w = f2bf(v.w);
    ((ushort4*)dst)[i] = o;
  }
}

// both weight tensors in one launch
__global__ void cvt_w2(const float* __restrict__ s1, unsigned short* __restrict__ d1,
                       int n1_4,
                       const float* __restrict__ s2, unsigned short* __restrict__ d2,
                       int n2_4) {
  int i = blockIdx.x * blockDim.x + threadIdx.x;
  const int stride = gridDim.x * blockDim.x;
  const int tot = n1_4 + n2_4;
  for (; i < tot; i += stride) {
    const float4 v = (i < n1_4) ? ((const float4*)s1)[i]
                                : ((const float4*)s2)[i - n1_4];
    ushort4 o;
    o.x = f2bf(v.x); o.y = f2bf(v.y); o.z = f2bf(v.z); o.w = f2bf(v.w);
    if (i < n1_4) ((ushort4*)d1)[i] = o;
    else          ((ushort4*)d2)[i - n1_4] = o;
  }
}

// ---------------------------------------------------------------- persistent 256x256 GEMM
// C = A @ B^T + bias. A: [M x K] bf16 K-fast, B: [N x K] bf16 K-fast.
// grid = M/256 blocks, 1/CU (128KB LDS). K-stream step s over n-tiles j.
// LDS regions: A(par,kh)=par*32768+kh*16384, B=+65536; par = s&1.
//   ph1 stage A-Kh1(s+1)   ph2 stage B-Kh1(s+1), vmcnt(8)
//   ph3 stage A-Kh0(s+2)   ph4 stage B-Kh0(s+2), vmcnt(8)
// Swizzle: byte p ^= ((p>>7)&3)<<4 pre-applied on global source, applied on reads.
template <int OUT_BF16>
__global__ __launch_bounds__(512, 2) void gemm256p(
    const unsigned short* __restrict__ A, const unsigned short* __restrict__ B,
    const float* __restrict__ bias, void* __restrict__ Cout,
    int M, int N, int K) {
  extern __shared__ char lds[];

  const int tid  = threadIdx.x;
  const int lane = tid & 63;
  const int wid  = tid >> 6;
  const int g16  = (lane >> 4) & 3;
  const int l15  = lane & 15;
  const int wm   = wid >> 2;
  const int wn   = wid & 3;

  const size_t bm = (size_t)blockIdx.x << 8;
  const int NT = K >> 6;
  const int NB = N >> 8;
  const int TT = NB * NT;

  const int srow = tid >> 2;
  const int csel = (((tid & 3) ^ ((tid >> 3) & 3)) << 3);
  const int ldst = wid * 1024;
  const unsigned short* pA0 = A + (bm + srow) * (size_t)K + csel;
  const unsigned short* pA1 = pA0 + (size_t)128 * K;
  const unsigned short* pB0 = B + (size_t)srow * K + csel;
  const unsigned short* pB1 = pB0 + (size_t)128 * K;

#define STAGE_A(koff, regbase)                                          \
  do {                                                                  \
    GLOAD_LDS16(pA0 + (koff), lds + (regbase) + ldst);                  \
    GLOAD_LDS16(pA1 + (koff), lds + (regbase) + 8192 + ldst);           \
  } while (0)
#define STAGE_B(boff, regbase)                                          \
  do {                                                                  \
    GLOAD_LDS16(pB0 + (boff), lds + (regbase) + ldst);                  \
    GLOAD_LDS16(pB1 + (boff), lds + (regbase) + 8192 + ldst);           \
  } while (0)

  const int s16  = ((g16 ^ ((l15 >> 1) & 3)) << 4);
  const int offA = (wm * 128 + l15) * 64 + s16;
  const int offB = (wn * 64 + l15) * 64 + s16;

  f32x4 acc[8][4];
  const f32x4 zero4 = {0.f, 0.f, 0.f, 0.f};
#pragma unroll
  for (int i = 0; i < 8; ++i)
#pragma unroll
    for (int j = 0; j < 4; ++j) acc[i][j] = zero4;

#define READ_A(par, kk, rh)                                              \
  { const char* rb = lds + (par) * 32768 + (kk) * 16384 + offA + (rh) * 4096; \
    af[0] = *(const bf16x8*)(rb);                                        \
    af[1] = *(const bf16x8*)(rb + 1024);                                 \
    af[2] = *(const bf16x8*)(rb + 2048);                                 \
    af[3] = *(const bf16x8*)(rb + 3072); }
#define READ_B(par, kk)                                                  \
  { const char* rb = lds + 65536 + (par) * 32768 + (kk) * 16384 + offB;  \
    bfv[0] = *(const bf16x8*)(rb);                                       \
    bfv[1] = *(const bf16x8*)(rb + 1024);                                \
    bfv[2] = *(const bf16x8*)(rb + 2048);                                \
    bfv[3] = *(const bf16x8*)(rb + 3072); }
#define MFMA16(rh)                                                       \
  _Pragma("unroll") for (int q = 0; q < 4; ++q)                          \
  _Pragma("unroll") for (int c = 0; c < 4; ++c)                          \
    acc[(rh) * 4 + q][c] = __builtin_amdgcn_mfma_f32_16x16x32_bf16(      \
        af[q], bfv[c], acc[(rh) * 4 + q][c], 0, 0, 0);
#define BAR() __builtin_amdgcn_s_barrier()
#define VMCNT8() asm volatile("s_waitcnt vmcnt(8)" ::: "memory")

  int    kk  = 0;
  int    bnC = 0;
  int    k1  = 64;
  int    k2  = 128;
  size_t rB1 = 0;
  size_t rB2 = 0;

  STAGE_A(0, 0);
  STAGE_B(0, 65536);
  STAGE_A(32, 16384);
  STAGE_B(32, 65536 + 16384);
  STAGE_A(64, 32768);
  STAGE_B(64, 65536 + 32768);
  VMCNT8();
  BAR();

  for (int s = 0; s < TT; ++s) {
    const int par  = s & 1;
    const int parn = par ^ 1;
    bf16x8 af[4], bfv[4];

    READ_A(par, 0, 0); READ_B(par, 0);
    STAGE_A(k1 + 32, parn * 32768 + 16384);
    BAR();
    __builtin_amdgcn_s_setprio(1); MFMA16(0); __builtin_amdgcn_s_setprio(0);
    BAR();

    READ_A(par, 0, 1);
    STAGE_B(rB1 + k1 + 32, 65536 + parn * 32768 + 16384);
    VMCNT8();
    BAR();
    __builtin_amdgcn_s_setprio(1); MFMA16(1); __builtin_amdgcn_s_setprio(0);
    BAR();

    READ_A(par, 1, 0); READ_B(par, 1);
    STAGE_A(k2, par * 32768);
    BAR();
    __builtin_amdgcn_s_setprio(1); MFMA16(0); __builtin_amdgcn_s_setprio(0);
    BAR();

    READ_A(par, 1, 1);
    STAGE_B(rB2 + k2, 65536 + par * 32768);
    VMCNT8();
    BAR();
    __builtin_amdgcn_s_setprio(1); MFMA16(1); __builtin_amdgcn_s_setprio(0);
    BAR();

    if (kk == NT - 1) {
#pragma unroll
      for (int ai = 0; ai < 8; ++ai) {
        const size_t row0 =
            bm + wm * 128 + (ai >> 2) * 64 + (ai & 3) * 16 + g16 * 4;
#pragma unroll
        for (int c = 0; c < 4; ++c) {
          const int col = bnC + wn * 64 + c * 16 + l15;
          const float bv = bias[col];
#pragma unroll
          for (int r = 0; r < 4; ++r) {
            const float v = acc[ai][c][r] + bv;
            const size_t idx = (row0 + r) * (size_t)N + col;
            if (OUT_BF16) ((unsigned short*)Cout)[idx] = f2bf(v);
            else          ((float*)Cout)[idx] = v;
          }
          acc[ai][c] = zero4;
        }
      }
      bnC += 256;
      kk = 0;
    } else {
      ++kk;
    }

    k1 = k2; rB1 = rB2;
    if (s + 3 < TT) {
      k2 += 64;
      if (k2 == K) { k2 = 0; rB2 += (size_t)256 * K; }
    }
  }
#undef STAGE_A
#undef STAGE_B
#undef READ_A
#undef READ_B
#undef MFMA16
#undef BAR
#undef VMCNT8
}

// ---------------------------------------------------------------- per-tile 256x256 GEMM
// C = A @ B^T + bias, both bf16 K-fast. (Proj kernel.)
template <int OUT_BF16>
__global__ __launch_bounds__(512, 2) void gemm256t(
    const unsigned short* __restrict__ A, const unsigned short* __restrict__ B,
    const float* __restrict__ bias, void* __restrict__ Cout,
    int M, int N, int K) {
  extern __shared__ char lds[];

  const int tid  = threadIdx.x;
  const int lane = tid & 63;
  const int wid  = tid >> 6;
  const int g16  = (lane >> 4) & 3;
  const int l15  = lane & 15;
  const int wm   = wid >> 2;
  const int wn   = wid & 3;

  const int nbn = N >> 8;
  const int wg  = (blockIdx.x & 7) * ((int)gridDim.x >> 3) + (blockIdx.x >> 3);
  const size_t bm = (size_t)(wg / nbn) << 8;
  const size_t bn = (size_t)(wg % nbn) << 8;

  const int NT = K >> 6;

  const int srow = tid >> 2;
  const int csel = (((tid & 3) ^ ((tid >> 3) & 3)) << 3);
  const int ldst = wid * 1024;
  const unsigned short* pA0 = A + (bm + srow) * (size_t)K + csel;
  const unsigned short* pA1 = pA0 + (size_t)128 * K;
  const unsigned short* pB0 = B + (bn + srow) * (size_t)K + csel;
  const unsigned short* pB1 = pB0 + (size_t)128 * K;

#define STAGE(p0, p1, kcol, regbase)                                   \
  do {                                                                 \
    GLOAD_LDS16((p0) + (kcol), lds + (regbase) + ldst);                \
    GLOAD_LDS16((p1) + (kcol), lds + (regbase) + 8192 + ldst);         \
  } while (0)

  const int s16  = ((g16 ^ ((l15 >> 1) & 3)) << 4);
  const int offA = (wm * 128 + l15) * 64 + s16;
  const int offB = (wn * 64 + l15) * 64 + s16;

  f32x4 acc[8][4];
  const f32x4 zero4 = {0.f, 0.f, 0.f, 0.f};
#pragma unroll
  for (int i = 0; i < 8; ++i)
#pragma unroll
    for (int j = 0; j < 4; ++j) acc[i][j] = zero4;

#define READ_A(par, kk, rh)                                              \
  { const char* rb = lds + (par) * 32768 + (kk) * 16384 + offA + (rh) * 4096; \
    af[0] = *(const bf16x8*)(rb);                                        \
    af[1] = *(const bf16x8*)(rb + 1024);                                 \
    af[2] = *(const bf16x8*)(rb + 2048);                                 \
    af[3] = *(const bf16x8*)(rb + 3072); }
#define READ_B(par, kk)                                                  \
  { const char* rb = lds + 65536 + (par) * 32768 + (kk) * 16384 + offB;  \
    bfv[0] = *(const bf16x8*)(rb);                                       \
    bfv[1] = *(const bf16x8*)(rb + 1024);                                \
    bfv[2] = *(const bf16x8*)(rb + 2048);                                \
    bfv[3] = *(const bf16x8*)(rb + 3072); }
#define MFMA16(rh)                                                       \
  _Pragma("unroll") for (int q = 0; q < 4; ++q)                          \
  _Pragma("unroll") for (int c = 0; c < 4; ++c)                          \
    acc[(rh) * 4 + q][c] = __builtin_amdgcn_mfma_f32_16x16x32_bf16(      \
        af[q], bfv[c], acc[(rh) * 4 + q][c], 0, 0, 0);
#define BAR() __builtin_amdgcn_s_barrier()
#define VMCNT8() asm volatile("s_waitcnt vmcnt(8)" ::: "memory")

  STAGE(pA0, pA1, 0, 0);
  STAGE(pB0, pB1, 0, 65536);
  STAGE(pA0, pA1, 32, 16384);
  STAGE(pB0, pB1, 32, 65536 + 16384);
  {
    const int k1 = (NT > 1 ? 64 : 0);
    STAGE(pA0, pA1, k1, 32768);
    STAGE(pB0, pB1, k1, 65536 + 32768);
  }
  VMCNT8();
  BAR();

  for (int t = 0; t < NT; ++t) {
    const int par  = t & 1;
    const int parn = par ^ 1;
    const int kc1  = (t + 1 < NT ? t + 1 : NT - 1) * 64;
    const int kc2  = (t + 2 < NT ? t + 2 : NT - 1) * 64;
    bf16x8 af[4], bfv[4];

    READ_A(par, 0, 0); READ_B(par, 0);
    STAGE(pA0, pA1, kc1 + 32, parn * 32768 + 16384);
    BAR();
    __builtin_amdgcn_s_setprio(1); MFMA16(0); __builtin_amdgcn_s_setprio(0);
    BAR();

    READ_A(par, 0, 1);
    STAGE(pB0, pB1, kc1 + 32, 65536 + parn * 32768 + 16384);
    VMCNT8();
    BAR();
    __builtin_amdgcn_s_setprio(1); MFMA16(1); __builtin_amdgcn_s_setprio(0);
    BAR();

    READ_A(par, 1, 0); READ_B(par, 1);
    STAGE(pA0, pA1, kc2, par * 32768);
    BAR();
    __builtin_amdgcn_s_setprio(1); MFMA16(0); __builtin_amdgcn_s_setprio(0);
    BAR();

    READ_A(par, 1, 1);
    STAGE(pB0, pB1, kc2, 65536 + par * 32768);
    VMCNT8();
    BAR();
    __builtin_amdgcn_s_setprio(1); MFMA16(1); __builtin_amdgcn_s_setprio(0);
    BAR();
  }

#pragma unroll
  for (int ai = 0; ai < 8; ++ai) {
    const size_t row0 = bm + wm * 128 + (ai >> 2) * 64 + (ai & 3) * 16 + g16 * 4;
#pragma unroll
    for (int c = 0; c < 4; ++c) {
      const size_t col = bn + wn * 64 + c * 16 + l15;
      const float bv = bias[col];
#pragma unroll
      for (int r = 0; r < 4; ++r) {
        const float v = acc[ai][c][r] + bv;
        const size_t idx = (row0 + r) * N + col;
        if (OUT_BF16) ((unsigned short*)Cout)[idx] = f2bf(v);
        else          ((float*)Cout)[idx] = v;
      }
    }
  }
#undef STAGE
#undef READ_A
#undef READ_B
#undef MFMA16
#undef BAR
#undef VMCNT8
}

// ---------------------------------------------------------------- fused mask-unit attention
// One block (256 thr, 4 waves) per (b,h,w). (R7-exact.)
__global__ __launch_bounds__(256) void attn_kernel(
    const unsigned short* __restrict__ qkv,   // [65536 x 2304] bf16
    float* __restrict__ attn_out,             // [b,h,w,64,256] fp32
    unsigned short* __restrict__ Xws) {       // [16384 x 768] bf16
  __shared__ unsigned short smem[32768];
  char* KP = (char*)smem;             // 32KB K region / later P region
  char* VT = (char*)(smem + 16384);   // 32KB V transposed [d][s]

  const int tid  = threadIdx.x;
  const int lane = tid & 63;
  const int wid  = tid >> 6;
  const int g16  = lane >> 4;
  const int l15  = lane & 15;

  const int bid = blockIdx.x;         // ((b*12 + h)*32 + w)
  const int w = bid & 31;
  const int h = (bid >> 5) % 12;
  const int b = bid / 384;

  const int s0 = tid >> 3;            // 0..31
  const int part = tid & 7;

#pragma unroll
  for (int p = 0; p < 8; ++p) {
    const int s = s0 + p * 32;
    const size_t gbase =
        ((size_t)b * 8192 + (size_t)s * 32 + w) * 2304 + h * 64 + part * 8;
    int4 kv = *(const int4*)(qkv + gbase + 768);
    *(int4*)(KP + ((s * 128 + part * 16) ^ ((s & 7) << 4))) = kv;
  }

#pragma unroll
  for (int p = 0; p < 2; ++p) {
    const int s = s0 * 4 + p * 128;
    const size_t gb0 =
        ((size_t)b * 8192 + (size_t)s * 32 + w) * 2304 + 1536 + h * 64 + part * 8;
    int4 x0 = *(const int4*)(qkv + gb0);
    int4 x1 = *(const int4*)(qkv + gb0 + 73728);
    int4 x2 = *(const int4*)(qkv + gb0 + 147456);
    int4 x3 = *(const int4*)(qkv + gb0 + 221184);
    const unsigned int* u0 = (const unsigned int*)&x0;
    const unsigned int* u1 = (const unsigned int*)&x1;
    const unsigned int* u2 = (const unsigned int*)&x2;
    const unsigned int* u3 = (const unsigned int*)&x3;
#pragma unroll
    for (int k = 0; k < 4; ++k) {
      const unsigned int lo01 = (u0[k] & 0xffffu) | (u1[k] << 16);
      const unsigned int lo23 = (u2[k] & 0xffffu) | (u3[k] << 16);
      const unsigned int hi01 = (u0[k] >> 16) | (u1[k] & 0xffff0000u);
      const unsigned int hi23 = (u2[k] >> 16) | (u3[k] & 0xffff0000u);
      const int dlo = part * 8 + 2 * k;
      const int dhi = dlo + 1;
      uint2 vlo; vlo.x = lo01; vlo.y = lo23;
      uint2 vhi; vhi.x = hi01; vhi.y = hi23;
      *(uint2*)(VT + ((dlo * 512 + s * 2) ^ ((dlo & 7) << 4))) = vlo;
      *(uint2*)(VT + ((dhi * 512 + s * 2) ^ ((dhi & 7) << 4))) = vhi;
    }
  }

  union BU { unsigned short u[8]; bf16x8 v; };
  BU aq0, aq1;
  {
    const int qrow = wid * 16 + l15;
    float q0[8], q1[8];
#pragma unroll
    for (int j = 0; j < 8; ++j) { q0[j] = -1e30f; q1[j] = -1e30f; }
#pragma unroll
    for (int g = 0; g < 4; ++g) {
      const size_t gbase =
          ((size_t)b * 8192 + (size_t)(g * 64 + qrow) * 32 + w) * 2304 +
          h * 64 + g16 * 8;
      int4 a = *(const int4*)(qkv + gbase);
      int4 c = *(const int4*)(qkv + gbase + 32);
      const unsigned short* pa = (const unsigned short*)&a;
      const unsigned short* pc = (const unsigned short*)&c;
#pragma unroll
      for (int j = 0; j < 8; ++j) {
        q0[j] = fmaxf(q0[j], bf2f(pa[j]));
        q1[j] = fmaxf(q1[j], bf2f(pc[j]));
      }
    }
#pragma unroll
    for (int j = 0; j < 8; ++j) {
      aq0.u[j] = (unsigned short)(__float_as_uint(q0[j]) >> 16);
      aq1.u[j] = (unsigned short)(__float_as_uint(q1[j]) >> 16);
    }
  }

  __syncthreads();

  f32x4 sacc[16];
  const f32x4 zero4 = {0.f, 0.f, 0.f, 0.f};
#pragma unroll
  for (int t = 0; t < 16; ++t) sacc[t] = zero4;
#pragma unroll
  for (int t = 0; t < 16; ++t) {
    const int srow = t * 16 + l15;
    bf16x8 bk0 = *(const bf16x8*)(KP + ((srow * 128 + 0  + g16 * 16) ^ ((srow & 7) << 4)));
    bf16x8 bk1 = *(const bf16x8*)(KP + ((srow * 128 + 64 + g16 * 16) ^ ((srow & 7) << 4)));
    sacc[t] = __builtin_amdgcn_mfma_f32_16x16x32_bf16(aq0.v, bk0, sacc[t], 0, 0, 0);
    sacc[t] = __builtin_amdgcn_mfma_f32_16x16x32_bf16(aq1.v, bk1, sacc[t], 0, 0, 0);
  }

  float inv_[4];
#pragma unroll
  for (int r = 0; r < 4; ++r) {
    float m = -1e30f;
#pragma unroll
    for (int t = 0; t < 16; ++t) { sacc[t][r] *= 0.125f; m = fmaxf(m, sacc[t][r]); }
#pragma unroll
    for (int off = 1; off < 16; off <<= 1) m = fmaxf(m, __shfl_xor(m, off, 64));
    float ssum = 0.f;
#pragma unroll
    for (int t = 0; t < 16; ++t) {
      float e = expf(sacc[t][r] - m);
      sacc[t][r] = e;
      ssum += e;
    }
#pragma unroll
    for (int off = 1; off < 16; off <<= 1) ssum += __shfl_xor(ssum, off, 64);
    inv_[r] = 1.f / ssum;
  }

  {
    float* ab = attn_out + ((size_t)bid * 64 + wid * 16) * 256;
#pragma unroll
    for (int t = 0; t < 16; ++t)
#pragma unroll
      for (int r = 0; r < 4; ++r) {
        const float p = sacc[t][r] * inv_[r];
        sacc[t][r] = p;
        ab[(size_t)(g16 * 4 + r) * 256 + t * 16 + l15] = p;
      }
  }

  __syncthreads();

  {
    char* PW = KP + wid * 8192;
#pragma unroll
    for (int t = 0; t < 16; ++t)
#pragma unroll
      for (int r = 0; r < 4; ++r) {
        const int row = g16 * 4 + r;
        *(unsigned short*)(PW + ((row * 512 + (t * 16 + l15) * 2) ^ ((row & 7) << 4))) =
            f2bf(sacc[t][r]);
      }
  }

  f32x4 oacc[4];
#pragma unroll
  for (int n = 0; n < 4; ++n) oacc[n] = zero4;
  {
    const char* PR = KP + wid * 8192;
#pragma unroll
    for (int kc = 0; kc < 8; ++kc) {
      bf16x8 pa = *(const bf16x8*)(PR + ((l15 * 512 + kc * 64 + g16 * 16) ^ ((l15 & 7) << 4)));
#pragma unroll
      for (int n = 0; n < 4; ++n) {
        const int d = n * 16 + l15;
        bf16x8 vv = *(const bf16x8*)(VT + ((d * 512 + kc * 64 + g16 * 16) ^ ((d & 7) << 4)));
        oacc[n] = __builtin_amdgcn_mfma_f32_16x16x32_bf16(pa, vv, oacc[n], 0, 0, 0);
      }
    }
  }

#pragma unroll
  for (int n = 0; n < 4; ++n)
#pragma unroll
    for (int r = 0; r < 4; ++r) {
      const int qi = wid * 16 + g16 * 4 + r;
      Xws[((size_t)b * 2048 + qi * 32 + w) * 768 + h * 64 + n * 16 + l15] =
          f2bf(oacc[n][r]);
    }
}

// ---------------------------------------------------------------- launch
extern "C" void kernel_launch(void* const* d_in, const int* in_sizes, int n_in,
                              void* d_out, int out_size, void* d_ws, size_t ws_size,
                              hipStream_t stream) {
  const float* emb    = (const float*)d_in[0];
  const float* qkv_w  = (const float*)d_in[1];
  const float* qkv_b  = (const float*)d_in[2];
  const float* proj_w = (const float*)d_in[3];
  const float* proj_b = (const float*)d_in[4];
  float* out = (float*)d_out;

  char* ws = (char*)d_ws;
  unsigned short* embB   = (unsigned short*)(ws);
  unsigned short* wqkvB  = (unsigned short*)(ws + 100663296);
  unsigned short* wprojB = (unsigned short*)(ws + 104202240);
  unsigned short* qkvB   = (unsigned short*)(ws + 105381888);
  unsigned short* Xws    = (unsigned short*)(ws + 407371776);

  // 1) fp32 -> bf16 conversions (weights merged into one launch)
  cvt_bf16<<<4096, 256, 0, stream>>>(emb, embB, 50331648 / 4);
  cvt_w2<<<2048, 256, 0, stream>>>(qkv_w, wqkvB, 1769472 / 4,
                                   proj_w, wprojB, 589824 / 4);

  // 2) qkv = emb @ qkv_w^T + qkv_b  (bf16 out; persistent 256^2, 128KB dyn LDS)
  hipFuncSetAttribute(reinterpret_cast<const void*>(&gemm256p<1>),
                      hipFuncAttributeMaxDynamicSharedMemorySize, 131072);
  gemm256p<1><<<256, 512, 131072, stream>>>(embB, wqkvB, qkv_b, qkvB,
                                            65536, 2304, 768);

  // 3) fused mask-unit attention (attn fp32 to d_out tail, X bf16 to ws)
  attn_kernel<<<3072, 256, 0, stream>>>(qkvB, out + 12582912, Xws);

  // 4) out = X @ proj_w^T + proj_b  (fp32 out; 256^2 per-tile, 192 blocks)
  hipFuncSetAttribute(reinterpret_cast<const void*>(&gemm256t<0>),
                      hipFuncAttributeMaxDynamicSharedMemorySize, 131072);
  gemm256t<0><<<192, 512, 131072, stream>>>(Xws, wprojB, proj_b, out,
                                            16384, 768, 768);
}